// Round 1
// baseline (841.173 us; speedup 1.0000x reference)
//
#include <hip/hip_runtime.h>
#include <hip/hip_bf16.h>
#include <stdint.h>

// Problem: out[b,l,a] = sum_{i<=l} sum_f feat[b,i,f] * W_l[i,f,a] + bias[l,a]
// B=64 L=12 DF=4096 DA=768. HBM-bound: weights = 981 MB read exactly once.
// Strategy: 78 (l,i) K-slabs x 6 N-tiles = 468 blocks, bf16 MFMA with
// in-register fp32->bf16 conversion of W, split-K accumulation via fp32
// HW atomics onto bias-initialized d_out. No LDS (wave-private fragments).

#define B_DIM 64
#define L_DIM 12
#define DF 4096
#define DA 768
#define NT 128              // N tile per block (4 waves x 32 cols)
#define NU 78               // sum_{l} (l+1)
#define NJ (DA / NT)        // 6
#define KSTEP 32
#define NSTEPS (DF / KSTEP) // 128

typedef __bf16 bf16_t;
typedef __bf16 bf16x8 __attribute__((ext_vector_type(8)));
typedef __bf16 bf16x4 __attribute__((ext_vector_type(4)));
typedef float f32x4 __attribute__((ext_vector_type(4)));

struct WPtrs { const float* W[L_DIM]; };

// ---------- features fp32 -> bf16 into workspace ----------
__global__ __launch_bounds__(256) void k_convert_feat(const float* __restrict__ in,
                                                      bf16_t* __restrict__ out) {
    const int idx = (blockIdx.x * 256 + threadIdx.x) * 4;
    const float4 v = *reinterpret_cast<const float4*>(in + idx);
    bf16x4 o;
    o[0] = (bf16_t)v.x; o[1] = (bf16_t)v.y; o[2] = (bf16_t)v.z; o[3] = (bf16_t)v.w;
    *reinterpret_cast<bf16x4*>(out + idx) = o;
}

// ---------- out = broadcast bias (d_out is poisoned 0xAA pre-call) ----------
__global__ __launch_bounds__(256) void k_init_out(const float* __restrict__ bias,
                                                  float* __restrict__ out) {
    const int idx = (blockIdx.x * 256 + threadIdx.x) * 4;   // 576*256*4 = 589824
    const int la = idx % (L_DIM * DA);
    *reinterpret_cast<float4*>(out + idx) = *reinterpret_cast<const float4*>(bias + la);
}

// ---------- main: per-(l,i,j) partial GEMM, atomic accumulate ----------
template <bool FEAT_BF16>
__global__ __launch_bounds__(256) void k_cross_gemm(const void* __restrict__ featv,
                                                    WPtrs wp,
                                                    float* __restrict__ out) {
    const int j = blockIdx.x;   // 0..5  N tile
    const int u = blockIdx.y;   // 0..77 flattened (l,i)
    int l = 0, base = 0;
    while (u >= base + l + 1) { base += l + 1; ++l; }
    const int i = u - base;

    const int tid  = threadIdx.x;
    const int wv   = tid >> 6;     // wave 0..3 -> n cols [wv*32, wv*32+32)
    const int lane = tid & 63;
    const int m16  = lane & 15;    // MFMA 16-dim lane index (m for A, n for B)
    const int q    = lane >> 4;    // quad: k offset = q*8 + e

    // B fragment base: W_l[i] row k = (k0 + q*8 + e), col = j*128 + wv*32 + ss*16 + m16
    const float* Wbase = wp.W[l] + (size_t)i * DF * DA + (size_t)(q * 8) * DA
                         + j * NT + wv * 32 + m16;
    // A fragment base: feat row b = mt*16 + m16, k offset q*8
    const size_t arow0 = ((size_t)m16 * L_DIM + i) * DF + q * 8;
    const size_t AROWSTEP = (size_t)16 * L_DIM * DF;   // mt stride (16 batch rows)
    const bf16_t* Ab = (const bf16_t*)featv + arow0;
    const float*  Af = (const float*)featv + arow0;

    bf16x8 a[2][4];     // [buf][mt]
    float  b[2][16];    // [buf][ss*8+e]
    f32x4  acc[4][2];
    #pragma unroll
    for (int mt = 0; mt < 4; ++mt)
        #pragma unroll
        for (int ss = 0; ss < 2; ++ss)
            acc[mt][ss] = (f32x4)(0.0f);

    auto loadA = [&](int k0, bf16x8* dst) {
        #pragma unroll
        for (int mt = 0; mt < 4; ++mt) {
            if constexpr (FEAT_BF16) {
                dst[mt] = *reinterpret_cast<const bf16x8*>(Ab + (size_t)mt * AROWSTEP + k0);
            } else {
                const float* p = Af + (size_t)mt * AROWSTEP + k0;
                const float4 f0 = *reinterpret_cast<const float4*>(p);
                const float4 f1 = *reinterpret_cast<const float4*>(p + 4);
                bf16x8 v;
                v[0] = (bf16_t)f0.x; v[1] = (bf16_t)f0.y; v[2] = (bf16_t)f0.z; v[3] = (bf16_t)f0.w;
                v[4] = (bf16_t)f1.x; v[5] = (bf16_t)f1.y; v[6] = (bf16_t)f1.z; v[7] = (bf16_t)f1.w;
                dst[mt] = v;
            }
        }
    };
    auto loadB = [&](int k0, float* dst) {
        const float* p = Wbase + (size_t)k0 * DA;
        #pragma unroll
        for (int ss = 0; ss < 2; ++ss)
            #pragma unroll
            for (int e = 0; e < 8; ++e)
                dst[ss * 8 + e] = p[(size_t)e * DA + ss * 16];
    };

    loadA(0, a[0]);
    loadB(0, b[0]);

    #pragma unroll 2
    for (int s = 0; s < NSTEPS; ++s) {
        const int cur = s & 1;
        if (s + 1 < NSTEPS) {
            loadA((s + 1) * KSTEP, a[cur ^ 1]);
            loadB((s + 1) * KSTEP, b[cur ^ 1]);
        }
        bf16x8 bfr[2];
        #pragma unroll
        for (int ss = 0; ss < 2; ++ss)
            #pragma unroll
            for (int e = 0; e < 8; ++e)
                bfr[ss][e] = (bf16_t)b[cur][ss * 8 + e];
        #pragma unroll
        for (int mt = 0; mt < 4; ++mt)
            #pragma unroll
            for (int ss = 0; ss < 2; ++ss)
                acc[mt][ss] = __builtin_amdgcn_mfma_f32_16x16x32_bf16(
                    a[cur][mt], bfr[ss], acc[mt][ss], 0, 0, 0);
    }

    // epilogue: C layout col = lane&15 (n), row = q*4 + reg (m). Atomic split-K add.
    #pragma unroll
    for (int mt = 0; mt < 4; ++mt) {
        #pragma unroll
        for (int ss = 0; ss < 2; ++ss) {
            const int col = j * NT + wv * 32 + ss * 16 + m16;
            #pragma unroll
            for (int r = 0; r < 4; ++r) {
                const int row = mt * 16 + q * 4 + r;   // batch index
                unsafeAtomicAdd(&out[((size_t)row * L_DIM + l) * DA + col], acc[mt][ss][r]);
            }
        }
    }
}

extern "C" void kernel_launch(void* const* d_in, const int* in_sizes, int n_in,
                              void* d_out, int out_size, void* d_ws, size_t ws_size,
                              hipStream_t stream) {
    const float* feat = (const float*)d_in[0];
    const float* bias = (const float*)d_in[1];
    WPtrs wp;
    for (int l = 0; l < L_DIM; ++l) wp.W[l] = (const float*)d_in[2 + l];
    float* out = (float*)d_out;

    // 1) out <- bias (d_out poisoned every call)
    k_init_out<<<dim3((B_DIM * L_DIM * DA) / 1024), dim3(256), 0, stream>>>(bias, out);

    const size_t need = (size_t)B_DIM * L_DIM * DF * sizeof(bf16_t);
    if (d_ws != nullptr && ws_size >= need) {
        // 2) features -> bf16 in workspace, 3) main GEMM reading bf16 A
        bf16_t* fb = (bf16_t*)d_ws;
        k_convert_feat<<<dim3((B_DIM * L_DIM * DF) / 1024), dim3(256), 0, stream>>>(feat, fb);
        k_cross_gemm<true><<<dim3(NJ, NU), dim3(256), 0, stream>>>((const void*)fb, wp, out);
    } else {
        // fallback: read fp32 features directly (slightly more L2 traffic)
        k_cross_gemm<false><<<dim3(NJ, NU), dim3(256), 0, stream>>>((const void*)feat, wp, out);
    }
}